// Round 1
// baseline (587.217 us; speedup 1.0000x reference)
//
#include <hip/hip_runtime.h>
#include <math.h>

#define N_NODES 50000
#define N_EDGES 800000
#define EPS 1e-7f
#define NEG_SLOPE 0.01f

#define NPB 32            // nodes per block
#define BLOCK 512         // 8 waves
#define NODES_PER_WAVE 4  // NPB / 8 waves
#define ROWS_PER_THREAD 4 // NPB*64 outputs / BLOCK threads

// ---------------- CSR build ----------------

__global__ void hist_kernel(const int* __restrict__ dst, int* __restrict__ cnt) {
    int i = blockIdx.x * blockDim.x + threadIdx.x;
    if (i < N_EDGES) atomicAdd(&cnt[dst[i]], 1);
}

__global__ __launch_bounds__(1024) void scan_kernel(const int* __restrict__ cnt,
                                                    int* __restrict__ off,
                                                    int* __restrict__ cursor) {
    __shared__ int sdata[1024];
    const int t = threadIdx.x;
    const int C = (N_NODES + 1023) / 1024;  // 49
    int beg = t * C;
    int end = beg + C; if (end > N_NODES) end = N_NODES;
    int sum = 0;
    for (int i = beg; i < end; ++i) sum += cnt[i];
    sdata[t] = sum;
    __syncthreads();
    // Hillis-Steele inclusive scan
    for (int st = 1; st < 1024; st <<= 1) {
        int v = (t >= st) ? sdata[t - st] : 0;
        __syncthreads();
        sdata[t] += v;
        __syncthreads();
    }
    int run = (t == 0) ? 0 : sdata[t - 1];
    for (int i = beg; i < end; ++i) {
        off[i] = run;
        cursor[i] = run;
        run += cnt[i];
    }
    if (t == 0) off[N_NODES] = N_EDGES;
}

__global__ void scatter_kernel(const int* __restrict__ dst, int* __restrict__ cursor,
                               int* __restrict__ perm) {
    int i = blockIdx.x * blockDim.x + threadIdx.x;
    if (i < N_EDGES) {
        int p = atomicAdd(&cursor[dst[i]], 1);
        perm[p] = i;
    }
}

// ---------------- fused aggregation + projection ----------------

__global__ __launch_bounds__(BLOCK) void main_kernel(
    const float* __restrict__ feat, const float* __restrict__ pos,
    const int* __restrict__ src,
    const float* __restrict__ W_self, const float* __restrict__ W_sp,
    const float* __restrict__ b_sp, const float* __restrict__ W_neigh,
    const float* __restrict__ b_neigh, const float* __restrict__ bias,
    const int* __restrict__ off, const int* __restrict__ perm,
    float* __restrict__ out)
{
    __shared__ float Wn[64 * 257];     // W_neigh[o][j] at o*257+j (odd stride: conflict-free)
    __shared__ float Ws[64 * 65];      // W_self[o][i] at o*65+i
    __shared__ float accS[NPB * 256];  // neigh_h[r][j]
    __shared__ float featS[NPB * 64];  // feat rows of this block's nodes

    const int t = threadIdx.x;
    const int lane = t & 63;
    const int w = t >> 6;
    const int nodeBase = blockIdx.x * NPB;

    // stage weights: coalesced global read, lane-consecutive LDS write (conflict-free)
    for (int m = t; m < 64 * 256; m += BLOCK) {
        int o = m >> 8, j = m & 255;
        Wn[o * 257 + j] = W_neigh[m];
    }
    for (int m = t; m < 64 * 64; m += BLOCK) {
        int o = m >> 6, i = m & 63;
        Ws[o * 65 + i] = W_self[m];
    }

    // per-lane spatial-MLP rows: lane = feature index i, handles j = lane*4+h
    float wsp0[4], wsp1[4], wsp2[4], bsp[4];
#pragma unroll
    for (int h = 0; h < 4; ++h) {
        int j = lane * 4 + h;
        wsp0[h] = W_sp[j * 3 + 0];
        wsp1[h] = W_sp[j * 3 + 1];
        wsp2[h] = W_sp[j * 3 + 2];
        bsp[h] = b_sp[j];
    }

    // ---- aggregation: wave w handles rows w*4 .. w*4+3 ----
    for (int q = 0; q < NODES_PER_WAVE; ++q) {
        const int r = w * NODES_PER_WAVE + q;
        const int n = nodeBase + r;
        if (n < N_NODES) {
            const int beg = off[n], end = off[n + 1];
            const float pdx = pos[n * 3 + 0];
            const float pdy = pos[n * 3 + 1];
            const float pdz = pos[n * 3 + 2];
            featS[r * 64 + lane] = feat[n * 64 + lane];
            float a0 = 0.f, a1 = 0.f, a2 = 0.f, a3 = 0.f;

#define EDGE_BODY(SN, MSK)                                                    \
            {                                                                 \
                float rx = pdx - pos[(SN) * 3 + 0];                           \
                float ry = pdy - pos[(SN) * 3 + 1];                           \
                float rz = pdz - pos[(SN) * 3 + 2];                           \
                float inv = 1.f / (sqrtf(rx * rx + ry * ry + rz * rz) + EPS); \
                float wx = (rx + 1.f) * inv;                                  \
                float wy = (ry + 1.f) * inv;                                  \
                float wz = (rz + 1.f) * inv;                                  \
                float f = feat[(SN) * 64 + lane] * (MSK);                     \
                float t0 = wx * wsp0[0] + wy * wsp1[0] + wz * wsp2[0] + bsp[0]; \
                float t1 = wx * wsp0[1] + wy * wsp1[1] + wz * wsp2[1] + bsp[1]; \
                float t2 = wx * wsp0[2] + wy * wsp1[2] + wz * wsp2[2] + bsp[2]; \
                float t3 = wx * wsp0[3] + wy * wsp1[3] + wz * wsp2[3] + bsp[3]; \
                t0 = t0 > 0.f ? t0 : NEG_SLOPE * t0;                          \
                t1 = t1 > 0.f ? t1 : NEG_SLOPE * t1;                          \
                t2 = t2 > 0.f ? t2 : NEG_SLOPE * t2;                          \
                t3 = t3 > 0.f ? t3 : NEG_SLOPE * t3;                          \
                a0 += t0 * f; a1 += t1 * f; a2 += t2 * f; a3 += t3 * f;       \
            }

            // 4-edge unroll: 4 independent load chains per iteration
            for (int k = beg; k < end; k += 4) {
                int rem = end - k;
                int i1 = rem > 1 ? 1 : 0;
                int i2 = rem > 2 ? 2 : 0;
                int i3 = rem > 3 ? 3 : 0;
                int e0 = perm[k];
                int e1 = perm[k + i1];
                int e2 = perm[k + i2];
                int e3 = perm[k + i3];
                int s0 = src[e0], s1 = src[e1], s2 = src[e2], s3 = src[e3];
                float m1 = rem > 1 ? 1.f : 0.f;
                float m2 = rem > 2 ? 1.f : 0.f;
                float m3 = rem > 3 ? 1.f : 0.f;
                EDGE_BODY(s0, 1.f)
                EDGE_BODY(s1, m1)
                EDGE_BODY(s2, m2)
                EDGE_BODY(s3, m3)
            }
#undef EDGE_BODY

            float deg = (float)(end - beg);
            float mscale = 1.f / fmaxf(deg, 1.f);
            float4 v4 = make_float4(a0 * mscale, a1 * mscale, a2 * mscale, a3 * mscale);
            *reinterpret_cast<float4*>(&accS[r * 256 + lane * 4]) = v4;
        }
    }
    __syncthreads();

    // ---- projection: thread (o=lane, rows w*4..w*4+3) ----
    const int o = lane;
    const int r0 = w * ROWS_PER_THREAD;
    const float bb = b_neigh[o] + bias[o];
    float v0 = bb, v1 = bb, v2 = bb, v3 = bb;

    const float* Wno = &Wn[o * 257];
    const float* A0 = &accS[(r0 + 0) * 256];
    const float* A1 = &accS[(r0 + 1) * 256];
    const float* A2 = &accS[(r0 + 2) * 256];
    const float* A3 = &accS[(r0 + 3) * 256];
    for (int j = 0; j < 256; j += 4) {
        float w0 = Wno[j + 0], w1 = Wno[j + 1], w2 = Wno[j + 2], w3 = Wno[j + 3];
        float4 x0 = *reinterpret_cast<const float4*>(&A0[j]);
        float4 x1 = *reinterpret_cast<const float4*>(&A1[j]);
        float4 x2 = *reinterpret_cast<const float4*>(&A2[j]);
        float4 x3 = *reinterpret_cast<const float4*>(&A3[j]);
        v0 += w0 * x0.x + w1 * x0.y + w2 * x0.z + w3 * x0.w;
        v1 += w0 * x1.x + w1 * x1.y + w2 * x1.z + w3 * x1.w;
        v2 += w0 * x2.x + w1 * x2.y + w2 * x2.z + w3 * x2.w;
        v3 += w0 * x3.x + w1 * x3.y + w2 * x3.z + w3 * x3.w;
    }

    const float* Wso = &Ws[o * 65];
    const float* F0 = &featS[(r0 + 0) * 64];
    const float* F1 = &featS[(r0 + 1) * 64];
    const float* F2 = &featS[(r0 + 2) * 64];
    const float* F3 = &featS[(r0 + 3) * 64];
    for (int i = 0; i < 64; i += 4) {
        float w0 = Wso[i + 0], w1 = Wso[i + 1], w2 = Wso[i + 2], w3 = Wso[i + 3];
        float4 x0 = *reinterpret_cast<const float4*>(&F0[i]);
        float4 x1 = *reinterpret_cast<const float4*>(&F1[i]);
        float4 x2 = *reinterpret_cast<const float4*>(&F2[i]);
        float4 x3 = *reinterpret_cast<const float4*>(&F3[i]);
        v0 += w0 * x0.x + w1 * x0.y + w2 * x0.z + w3 * x0.w;
        v1 += w0 * x1.x + w1 * x1.y + w2 * x1.z + w3 * x1.w;
        v2 += w0 * x2.x + w1 * x2.y + w2 * x2.z + w3 * x2.w;
        v3 += w0 * x3.x + w1 * x3.y + w2 * x3.z + w3 * x3.w;
    }

    const int n0 = nodeBase + r0;
    if (n0 + 0 < N_NODES) out[(n0 + 0) * 64 + o] = v0;
    if (n0 + 1 < N_NODES) out[(n0 + 1) * 64 + o] = v1;
    if (n0 + 2 < N_NODES) out[(n0 + 2) * 64 + o] = v2;
    if (n0 + 3 < N_NODES) out[(n0 + 3) * 64 + o] = v3;
}

// ---------------- launch ----------------

extern "C" void kernel_launch(void* const* d_in, const int* in_sizes, int n_in,
                              void* d_out, int out_size, void* d_ws, size_t ws_size,
                              hipStream_t stream) {
    (void)in_sizes; (void)n_in; (void)out_size; (void)ws_size;
    const float* feat    = (const float*)d_in[0];
    const float* pos     = (const float*)d_in[1];
    const int*   src     = (const int*)d_in[2];
    const int*   dst     = (const int*)d_in[3];
    const float* W_self  = (const float*)d_in[4];
    const float* W_sp    = (const float*)d_in[5];
    const float* b_sp    = (const float*)d_in[6];
    const float* W_neigh = (const float*)d_in[7];
    const float* b_neigh = (const float*)d_in[8];
    const float* bias    = (const float*)d_in[9];
    float* out = (float*)d_out;

    // workspace layout (all int32): cnt[N] | off[N+1] | cursor[N] | perm[E]  (~3.8 MB)
    int* cnt    = (int*)d_ws;
    int* off    = cnt + N_NODES;
    int* cursor = off + N_NODES + 1;
    int* perm   = cursor + N_NODES;

    hipMemsetAsync(cnt, 0, N_NODES * sizeof(int), stream);
    hist_kernel<<<(N_EDGES + 255) / 256, 256, 0, stream>>>(dst, cnt);
    scan_kernel<<<1, 1024, 0, stream>>>(cnt, off, cursor);
    scatter_kernel<<<(N_EDGES + 255) / 256, 256, 0, stream>>>(dst, cursor, perm);
    main_kernel<<<(N_NODES + NPB - 1) / NPB, BLOCK, 0, stream>>>(
        feat, pos, src, W_self, W_sp, b_sp, W_neigh, b_neigh, bias, off, perm, out);
}

// Round 2
// 441.797 us; speedup vs baseline: 1.3292x; 1.3292x over previous
//
#include <hip/hip_runtime.h>
#include <math.h>

#define N_NODES 50000
#define N_EDGES 800000
#define EPS 1e-7f
#define NEG_SLOPE 0.01f

// ---------------- CSR build ----------------

__global__ void hist_kernel(const int* __restrict__ dst, int* __restrict__ cnt) {
    int i = blockIdx.x * blockDim.x + threadIdx.x;
    if (i < N_EDGES) atomicAdd(&cnt[dst[i]], 1);
}

__global__ __launch_bounds__(1024) void scan_kernel(const int* __restrict__ cnt,
                                                    int* __restrict__ off,
                                                    int* __restrict__ cursor) {
    __shared__ int sdata[1024];
    const int t = threadIdx.x;
    const int C = (N_NODES + 1023) / 1024;  // 49
    int beg = t * C;
    int end = beg + C; if (end > N_NODES) end = N_NODES;
    int sum = 0;
    for (int i = beg; i < end; ++i) sum += cnt[i];
    sdata[t] = sum;
    __syncthreads();
    for (int st = 1; st < 1024; st <<= 1) {
        int v = (t >= st) ? sdata[t - st] : 0;
        __syncthreads();
        sdata[t] += v;
        __syncthreads();
    }
    int run = (t == 0) ? 0 : sdata[t - 1];
    for (int i = beg; i < end; ++i) {
        off[i] = run;
        cursor[i] = run;
        run += cnt[i];
    }
    if (t == 0) off[N_NODES] = N_EDGES;
}

// store SRC VALUES in dst-sorted order (removes one indirection from the hot loop)
__global__ void scatter_kernel(const int* __restrict__ src, const int* __restrict__ dst,
                               int* __restrict__ cursor, int* __restrict__ srcs) {
    int i = blockIdx.x * blockDim.x + threadIdx.x;
    if (i < N_EDGES) {
        int p = atomicAdd(&cursor[dst[i]], 1);
        srcs[p] = src[i];
    }
}

// ---------------- aggregation: one wave per node, no LDS ----------------

__device__ __forceinline__ unsigned pack_bf16(float a, float b) {
    return (__float_as_uint(a) >> 16) | (__float_as_uint(b) & 0xffff0000u);
}

__global__ __launch_bounds__(256) void aggregate_kernel(
    const float* __restrict__ feat, const float* __restrict__ pos,
    const float* __restrict__ W_sp, const float* __restrict__ b_sp,
    const int* __restrict__ off, const int* __restrict__ srcs,
    unsigned int* __restrict__ accp /* [N][128] bf16x2 */)
{
    const int lane = threadIdx.x & 63;
    const int n = (blockIdx.x << 2) + (threadIdx.x >> 6);  // 12500*4 == 50000 exact

    // per-lane spatial-MLP rows: lane = feature i, handles j = lane*4+h
    float wsp0[4], wsp1[4], wsp2[4], bsp[4];
#pragma unroll
    for (int h = 0; h < 4; ++h) {
        int j = lane * 4 + h;
        wsp0[h] = W_sp[j * 3 + 0];
        wsp1[h] = W_sp[j * 3 + 1];
        wsp2[h] = W_sp[j * 3 + 2];
        bsp[h]  = b_sp[j];
    }

    // wave-uniform loop bounds -> scalar registers
    const int beg = __builtin_amdgcn_readfirstlane(off[n]);
    const int end = __builtin_amdgcn_readfirstlane(off[n + 1]);
    const float pdx = pos[n * 3 + 0];
    const float pdy = pos[n * 3 + 1];
    const float pdz = pos[n * 3 + 2];
    float a0 = 0.f, a1 = 0.f, a2 = 0.f, a3 = 0.f;

#define EDGE_BODY(SN, MSK)                                                      \
    {                                                                           \
        float rx = pdx - pos[(SN) * 3 + 0];                                     \
        float ry = pdy - pos[(SN) * 3 + 1];                                     \
        float rz = pdz - pos[(SN) * 3 + 2];                                     \
        float d  = rx * rx + ry * ry + rz * rz;                                 \
        float inv = __builtin_amdgcn_rcpf(__builtin_amdgcn_sqrtf(d) + EPS);     \
        float wx = (rx + 1.f) * inv;                                            \
        float wy = (ry + 1.f) * inv;                                            \
        float wz = (rz + 1.f) * inv;                                            \
        float f  = feat[(SN) * 64 + lane] * (MSK);                              \
        float t0 = wx * wsp0[0] + wy * wsp1[0] + wz * wsp2[0] + bsp[0];         \
        float t1 = wx * wsp0[1] + wy * wsp1[1] + wz * wsp2[1] + bsp[1];         \
        float t2 = wx * wsp0[2] + wy * wsp1[2] + wz * wsp2[2] + bsp[2];         \
        float t3 = wx * wsp0[3] + wy * wsp1[3] + wz * wsp2[3] + bsp[3];         \
        t0 = t0 > 0.f ? t0 : t0 * NEG_SLOPE;                                    \
        t1 = t1 > 0.f ? t1 : t1 * NEG_SLOPE;                                    \
        t2 = t2 > 0.f ? t2 : t2 * NEG_SLOPE;                                    \
        t3 = t3 > 0.f ? t3 : t3 * NEG_SLOPE;                                    \
        a0 += t0 * f; a1 += t1 * f; a2 += t2 * f; a3 += t3 * f;                 \
    }

    for (int k = beg; k < end; k += 4) {
        const int rem = end - k;
        const int k1 = k + (rem > 1 ? 1 : 0);
        const int k2 = k + (rem > 2 ? 2 : 0);
        const int k3 = k + (rem > 3 ? 3 : 0);
        const int s0 = __builtin_amdgcn_readfirstlane(srcs[k]);
        const int s1 = __builtin_amdgcn_readfirstlane(srcs[k1]);
        const int s2 = __builtin_amdgcn_readfirstlane(srcs[k2]);
        const int s3 = __builtin_amdgcn_readfirstlane(srcs[k3]);
        const float m1 = rem > 1 ? 1.f : 0.f;
        const float m2 = rem > 2 ? 1.f : 0.f;
        const float m3 = rem > 3 ? 1.f : 0.f;
        EDGE_BODY(s0, 1.f)
        EDGE_BODY(s1, m1)
        EDGE_BODY(s2, m2)
        EDGE_BODY(s3, m3)
    }
#undef EDGE_BODY

    const float mscale = 1.f / fmaxf((float)(end - beg), 1.f);
    a0 *= mscale; a1 *= mscale; a2 *= mscale; a3 *= mscale;
    // lane holds j = lane*4 .. lane*4+3 -> two packed uints, coalesced uint2 store
    uint2 pv = make_uint2(pack_bf16(a0, a1), pack_bf16(a2, a3));
    *reinterpret_cast<uint2*>(&accp[(size_t)n * 128 + lane * 2]) = pv;
}

// ---------------- projection: out = acc@Wn^T + feat@Ws^T + b ----------------

__device__ __forceinline__ float bflo(unsigned u) { return __uint_as_float(u << 16); }
__device__ __forceinline__ float bfhi(unsigned u) { return __uint_as_float(u & 0xffff0000u); }

#define PRB 256

__global__ __launch_bounds__(PRB) void project_kernel(
    const float* __restrict__ feat, const unsigned int* __restrict__ accp,
    const float* __restrict__ W_neigh, const float* __restrict__ W_self,
    const float* __restrict__ b_neigh, const float* __restrict__ bias,
    float* __restrict__ out)
{
    // bf16-packed weights, odd pair-stride (129/33) -> conflict-free lane-strided reads
    __shared__ unsigned int WnP[64 * 129];  // 33 KB
    __shared__ unsigned int WsP[64 * 33];   // 8.4 KB   => 3 blocks/CU
    const int t = threadIdx.x;

    for (int m = t; m < 64 * 128; m += PRB) {
        int o = m >> 7, j2 = m & 127;
        float2 wv = *reinterpret_cast<const float2*>(&W_neigh[(o << 8) + (j2 << 1)]);
        WnP[o * 129 + j2] = pack_bf16(wv.x, wv.y);
    }
    for (int m = t; m < 64 * 32; m += PRB) {
        int o = m >> 5, i2 = m & 31;
        float2 wv = *reinterpret_cast<const float2*>(&W_self[(o << 6) + (i2 << 1)]);
        WsP[o * 33 + i2] = pack_bf16(wv.x, wv.y);
    }
    __syncthreads();

    const int o = t & 63;
    const int w = t >> 6;
    const int r0 = blockIdx.x * 16 + w * 4;  // 3125*16 == 50000 exact
    const float bb = b_neigh[o] + bias[o];
    float v0 = bb, v1 = bb, v2 = bb, v3 = bb;

    const unsigned int* A0 = accp + (size_t)(r0 + 0) * 128;
    const unsigned int* A1 = accp + (size_t)(r0 + 1) * 128;
    const unsigned int* A2 = accp + (size_t)(r0 + 2) * 128;
    const unsigned int* A3 = accp + (size_t)(r0 + 3) * 128;
    const unsigned int* Wo = &WnP[o * 129];
    for (int j2 = 0; j2 < 128; j2 += 2) {
        unsigned uw0 = Wo[j2], uw1 = Wo[j2 + 1];
        float w0 = bflo(uw0), w1 = bfhi(uw0), w2 = bflo(uw1), w3 = bfhi(uw1);
        uint2 x0 = *reinterpret_cast<const uint2*>(&A0[j2]);
        uint2 x1 = *reinterpret_cast<const uint2*>(&A1[j2]);
        uint2 x2 = *reinterpret_cast<const uint2*>(&A2[j2]);
        uint2 x3 = *reinterpret_cast<const uint2*>(&A3[j2]);
        v0 += w0 * bflo(x0.x) + w1 * bfhi(x0.x) + w2 * bflo(x0.y) + w3 * bfhi(x0.y);
        v1 += w0 * bflo(x1.x) + w1 * bfhi(x1.x) + w2 * bflo(x1.y) + w3 * bfhi(x1.y);
        v2 += w0 * bflo(x2.x) + w1 * bfhi(x2.x) + w2 * bflo(x2.y) + w3 * bfhi(x2.y);
        v3 += w0 * bflo(x3.x) + w1 * bfhi(x3.x) + w2 * bflo(x3.y) + w3 * bfhi(x3.y);
    }

    const float* F0 = feat + (size_t)(r0 + 0) * 64;
    const float* F1 = feat + (size_t)(r0 + 1) * 64;
    const float* F2 = feat + (size_t)(r0 + 2) * 64;
    const float* F3 = feat + (size_t)(r0 + 3) * 64;
    const unsigned int* Wso = &WsP[o * 33];
    for (int i2 = 0; i2 < 32; i2 += 2) {
        unsigned uw0 = Wso[i2], uw1 = Wso[i2 + 1];
        float w0 = bflo(uw0), w1 = bfhi(uw0), w2 = bflo(uw1), w3 = bfhi(uw1);
        float4 x0 = *reinterpret_cast<const float4*>(F0 + i2 * 2);
        float4 x1 = *reinterpret_cast<const float4*>(F1 + i2 * 2);
        float4 x2 = *reinterpret_cast<const float4*>(F2 + i2 * 2);
        float4 x3 = *reinterpret_cast<const float4*>(F3 + i2 * 2);
        v0 += w0 * x0.x + w1 * x0.y + w2 * x0.z + w3 * x0.w;
        v1 += w0 * x1.x + w1 * x1.y + w2 * x1.z + w3 * x1.w;
        v2 += w0 * x2.x + w1 * x2.y + w2 * x2.z + w3 * x2.w;
        v3 += w0 * x3.x + w1 * x3.y + w2 * x3.z + w3 * x3.w;
    }

    out[(size_t)(r0 + 0) * 64 + o] = v0;
    out[(size_t)(r0 + 1) * 64 + o] = v1;
    out[(size_t)(r0 + 2) * 64 + o] = v2;
    out[(size_t)(r0 + 3) * 64 + o] = v3;
}

// ---------------- launch ----------------

extern "C" void kernel_launch(void* const* d_in, const int* in_sizes, int n_in,
                              void* d_out, int out_size, void* d_ws, size_t ws_size,
                              hipStream_t stream) {
    (void)in_sizes; (void)n_in; (void)out_size; (void)ws_size;
    const float* feat    = (const float*)d_in[0];
    const float* pos     = (const float*)d_in[1];
    const int*   src     = (const int*)d_in[2];
    const int*   dst     = (const int*)d_in[3];
    const float* W_self  = (const float*)d_in[4];
    const float* W_sp    = (const float*)d_in[5];
    const float* b_sp    = (const float*)d_in[6];
    const float* W_neigh = (const float*)d_in[7];
    const float* b_neigh = (const float*)d_in[8];
    const float* bias    = (const float*)d_in[9];
    float* out = (float*)d_out;

    // ws layout: accp[N*128] uint (8B-aligned at base) | cnt[N] | off[N+1] | cursor[N] | srcs[E]
    unsigned int* accp = (unsigned int*)d_ws;
    int* cnt    = (int*)(accp + (size_t)N_NODES * 128);
    int* off    = cnt + N_NODES;
    int* cursor = off + N_NODES + 1;
    int* srcs   = cursor + N_NODES;

    hipMemsetAsync(cnt, 0, N_NODES * sizeof(int), stream);
    hist_kernel<<<(N_EDGES + 255) / 256, 256, 0, stream>>>(dst, cnt);
    scan_kernel<<<1, 1024, 0, stream>>>(cnt, off, cursor);
    scatter_kernel<<<(N_EDGES + 255) / 256, 256, 0, stream>>>(src, dst, cursor, srcs);
    aggregate_kernel<<<N_NODES / 4, 256, 0, stream>>>(feat, pos, W_sp, b_sp, off, srcs, accp);
    project_kernel<<<N_NODES / 16, PRB, 0, stream>>>(feat, accp, W_neigh, W_self,
                                                     b_neigh, bias, out);
}

// Round 3
// 335.215 us; speedup vs baseline: 1.7518x; 1.3180x over previous
//
#include <hip/hip_runtime.h>
#include <math.h>

#define N_NODES 50000
#define N_EDGES 800000
#define EPS 1e-7f
#define NEG_SLOPE 0.01f

#define SCAN_B 1024
#define SCAN_GRID ((N_NODES + SCAN_B - 1) / SCAN_B)  // 49

// ---------------- CSR build ----------------

__global__ void hist_kernel(const int* __restrict__ dst, int* __restrict__ cnt) {
    int i = blockIdx.x * blockDim.x + threadIdx.x;
    if (i < N_EDGES) atomicAdd(&cnt[dst[i]], 1);
}

// phase 1: per-block sums of cnt
__global__ __launch_bounds__(SCAN_B) void block_reduce_kernel(const int* __restrict__ cnt,
                                                              int* __restrict__ bsum) {
    __shared__ int sd[SCAN_B];
    const int t = threadIdx.x;
    const int i = blockIdx.x * SCAN_B + t;
    sd[t] = (i < N_NODES) ? cnt[i] : 0;
    __syncthreads();
    for (int st = SCAN_B / 2; st > 0; st >>= 1) {
        if (t < st) sd[t] += sd[t + st];
        __syncthreads();
    }
    if (t == 0) bsum[blockIdx.x] = sd[0];
}

// phase 2: exclusive scan of the 49 block sums (one wave)
__global__ __launch_bounds__(64) void scan_bsums_kernel(const int* __restrict__ bsum,
                                                        int* __restrict__ bofs) {
    const int lane = threadIdx.x;
    int orig = (lane < SCAN_GRID) ? bsum[lane] : 0;
    int v = orig;
    for (int d = 1; d < 64; d <<= 1) {
        int u = __shfl_up(v, d, 64);
        if (lane >= d) v += u;
    }
    if (lane < SCAN_GRID) bofs[lane] = v - orig;  // exclusive
}

// phase 3: per-block scan + add block offset, write off/cursor
__global__ __launch_bounds__(SCAN_B) void scan_write_kernel(const int* __restrict__ cnt,
                                                            const int* __restrict__ bofs,
                                                            int* __restrict__ off,
                                                            int* __restrict__ cursor) {
    __shared__ int sd[SCAN_B];
    const int t = threadIdx.x;
    const int i = blockIdx.x * SCAN_B + t;
    const int v = (i < N_NODES) ? cnt[i] : 0;
    sd[t] = v;
    __syncthreads();
    for (int st = 1; st < SCAN_B; st <<= 1) {
        int u = (t >= st) ? sd[t - st] : 0;
        __syncthreads();
        sd[t] += u;
        __syncthreads();
    }
    const int excl = sd[t] - v + bofs[blockIdx.x];
    if (i < N_NODES) {
        off[i] = excl;
        cursor[i] = excl;
    }
    if (i == N_NODES - 1) off[N_NODES] = excl + v;  // == N_EDGES
}

// store SRC VALUES in dst-sorted order (removes one indirection from the hot loop)
__global__ void scatter_kernel(const int* __restrict__ src, const int* __restrict__ dst,
                               int* __restrict__ cursor, int* __restrict__ srcs) {
    int i = blockIdx.x * blockDim.x + threadIdx.x;
    if (i < N_EDGES) {
        int p = atomicAdd(&cursor[dst[i]], 1);
        srcs[p] = src[i];
    }
}

// ---------------- aggregation: one wave per node, no LDS ----------------

__device__ __forceinline__ unsigned pack_bf16(float a, float b) {
    return (__float_as_uint(a) >> 16) | (__float_as_uint(b) & 0xffff0000u);
}

__global__ __launch_bounds__(256) void aggregate_kernel(
    const float* __restrict__ feat, const float* __restrict__ pos,
    const float* __restrict__ W_sp, const float* __restrict__ b_sp,
    const int* __restrict__ off, const int* __restrict__ srcs,
    unsigned int* __restrict__ accp /* [N][128] bf16x2 */)
{
    const int lane = threadIdx.x & 63;
    const int n = (blockIdx.x << 2) + (threadIdx.x >> 6);  // 12500*4 == 50000 exact

    // per-lane spatial-MLP rows: lane = feature i, handles j = lane*4+h
    float wsp0[4], wsp1[4], wsp2[4], bsp[4];
#pragma unroll
    for (int h = 0; h < 4; ++h) {
        int j = lane * 4 + h;
        wsp0[h] = W_sp[j * 3 + 0];
        wsp1[h] = W_sp[j * 3 + 1];
        wsp2[h] = W_sp[j * 3 + 2];
        bsp[h]  = b_sp[j];
    }

    // wave-uniform loop bounds -> scalar registers
    const int beg = __builtin_amdgcn_readfirstlane(off[n]);
    const int end = __builtin_amdgcn_readfirstlane(off[n + 1]);
    const float pdx = pos[n * 3 + 0];
    const float pdy = pos[n * 3 + 1];
    const float pdz = pos[n * 3 + 2];
    float a0 = 0.f, a1 = 0.f, a2 = 0.f, a3 = 0.f;

#define EDGE_BODY(SN, MSK)                                                      \
    {                                                                           \
        float rx = pdx - pos[(SN) * 3 + 0];                                     \
        float ry = pdy - pos[(SN) * 3 + 1];                                     \
        float rz = pdz - pos[(SN) * 3 + 2];                                     \
        float d  = rx * rx + ry * ry + rz * rz;                                 \
        float inv = __builtin_amdgcn_rcpf(__builtin_amdgcn_sqrtf(d) + EPS);     \
        float wx = (rx + 1.f) * inv;                                            \
        float wy = (ry + 1.f) * inv;                                            \
        float wz = (rz + 1.f) * inv;                                            \
        float f  = feat[(SN) * 64 + lane] * (MSK);                              \
        float t0 = wx * wsp0[0] + wy * wsp1[0] + wz * wsp2[0] + bsp[0];         \
        float t1 = wx * wsp0[1] + wy * wsp1[1] + wz * wsp2[1] + bsp[1];         \
        float t2 = wx * wsp0[2] + wy * wsp1[2] + wz * wsp2[2] + bsp[2];         \
        float t3 = wx * wsp0[3] + wy * wsp1[3] + wz * wsp2[3] + bsp[3];         \
        t0 = t0 > 0.f ? t0 : t0 * NEG_SLOPE;                                    \
        t1 = t1 > 0.f ? t1 : t1 * NEG_SLOPE;                                    \
        t2 = t2 > 0.f ? t2 : t2 * NEG_SLOPE;                                    \
        t3 = t3 > 0.f ? t3 : t3 * NEG_SLOPE;                                    \
        a0 += t0 * f; a1 += t1 * f; a2 += t2 * f; a3 += t3 * f;                 \
    }

    for (int k = beg; k < end; k += 4) {
        const int rem = end - k;
        const int k1 = k + (rem > 1 ? 1 : 0);
        const int k2 = k + (rem > 2 ? 2 : 0);
        const int k3 = k + (rem > 3 ? 3 : 0);
        const int s0 = __builtin_amdgcn_readfirstlane(srcs[k]);
        const int s1 = __builtin_amdgcn_readfirstlane(srcs[k1]);
        const int s2 = __builtin_amdgcn_readfirstlane(srcs[k2]);
        const int s3 = __builtin_amdgcn_readfirstlane(srcs[k3]);
        const float m1 = rem > 1 ? 1.f : 0.f;
        const float m2 = rem > 2 ? 1.f : 0.f;
        const float m3 = rem > 3 ? 1.f : 0.f;
        EDGE_BODY(s0, 1.f)
        EDGE_BODY(s1, m1)
        EDGE_BODY(s2, m2)
        EDGE_BODY(s3, m3)
    }
#undef EDGE_BODY

    const float mscale = 1.f / fmaxf((float)(end - beg), 1.f);
    a0 *= mscale; a1 *= mscale; a2 *= mscale; a3 *= mscale;
    // lane holds j = lane*4 .. lane*4+3 -> two packed uints, coalesced uint2 store
    uint2 pv = make_uint2(pack_bf16(a0, a1), pack_bf16(a2, a3));
    *reinterpret_cast<uint2*>(&accp[(size_t)n * 128 + lane * 2]) = pv;
}

// ---------------- projection: out = acc@Wn^T + feat@Ws^T + b ----------------

__device__ __forceinline__ float bflo(unsigned u) { return __uint_as_float(u << 16); }
__device__ __forceinline__ float bfhi(unsigned u) { return __uint_as_float(u & 0xffff0000u); }

#define PRB 256

__global__ __launch_bounds__(PRB) void project_kernel(
    const float* __restrict__ feat, const unsigned int* __restrict__ accp,
    const float* __restrict__ W_neigh, const float* __restrict__ W_self,
    const float* __restrict__ b_neigh, const float* __restrict__ bias,
    float* __restrict__ out)
{
    // bf16-packed weights, odd pair-stride (129/33) -> conflict-free lane-strided reads
    __shared__ unsigned int WnP[64 * 129];  // 33 KB
    __shared__ unsigned int WsP[64 * 33];   // 8.4 KB   => 3 blocks/CU
    const int t = threadIdx.x;

    for (int m = t; m < 64 * 128; m += PRB) {
        int o = m >> 7, j2 = m & 127;
        float2 wv = *reinterpret_cast<const float2*>(&W_neigh[(o << 8) + (j2 << 1)]);
        WnP[o * 129 + j2] = pack_bf16(wv.x, wv.y);
    }
    for (int m = t; m < 64 * 32; m += PRB) {
        int o = m >> 5, i2 = m & 31;
        float2 wv = *reinterpret_cast<const float2*>(&W_self[(o << 6) + (i2 << 1)]);
        WsP[o * 33 + i2] = pack_bf16(wv.x, wv.y);
    }
    __syncthreads();

    const int o = t & 63;
    const int w = t >> 6;
    const int r0 = blockIdx.x * 16 + w * 4;  // 3125*16 == 50000 exact
    const float bb = b_neigh[o] + bias[o];
    float v0 = bb, v1 = bb, v2 = bb, v3 = bb;

    const unsigned int* A0 = accp + (size_t)(r0 + 0) * 128;
    const unsigned int* A1 = accp + (size_t)(r0 + 1) * 128;
    const unsigned int* A2 = accp + (size_t)(r0 + 2) * 128;
    const unsigned int* A3 = accp + (size_t)(r0 + 3) * 128;
    const unsigned int* Wo = &WnP[o * 129];
    for (int j2 = 0; j2 < 128; j2 += 2) {
        unsigned uw0 = Wo[j2], uw1 = Wo[j2 + 1];
        float w0 = bflo(uw0), w1 = bfhi(uw0), w2 = bflo(uw1), w3 = bfhi(uw1);
        uint2 x0 = *reinterpret_cast<const uint2*>(&A0[j2]);
        uint2 x1 = *reinterpret_cast<const uint2*>(&A1[j2]);
        uint2 x2 = *reinterpret_cast<const uint2*>(&A2[j2]);
        uint2 x3 = *reinterpret_cast<const uint2*>(&A3[j2]);
        v0 += w0 * bflo(x0.x) + w1 * bfhi(x0.x) + w2 * bflo(x0.y) + w3 * bfhi(x0.y);
        v1 += w0 * bflo(x1.x) + w1 * bfhi(x1.x) + w2 * bflo(x1.y) + w3 * bfhi(x1.y);
        v2 += w0 * bflo(x2.x) + w1 * bfhi(x2.x) + w2 * bflo(x2.y) + w3 * bfhi(x2.y);
        v3 += w0 * bflo(x3.x) + w1 * bfhi(x3.x) + w2 * bflo(x3.y) + w3 * bfhi(x3.y);
    }

    const float* F0 = feat + (size_t)(r0 + 0) * 64;
    const float* F1 = feat + (size_t)(r0 + 1) * 64;
    const float* F2 = feat + (size_t)(r0 + 2) * 64;
    const float* F3 = feat + (size_t)(r0 + 3) * 64;
    const unsigned int* Wso = &WsP[o * 33];
    for (int i2 = 0; i2 < 32; i2 += 2) {
        unsigned uw0 = Wso[i2], uw1 = Wso[i2 + 1];
        float w0 = bflo(uw0), w1 = bfhi(uw0), w2 = bflo(uw1), w3 = bfhi(uw1);
        float4 x0 = *reinterpret_cast<const float4*>(F0 + i2 * 2);
        float4 x1 = *reinterpret_cast<const float4*>(F1 + i2 * 2);
        float4 x2 = *reinterpret_cast<const float4*>(F2 + i2 * 2);
        float4 x3 = *reinterpret_cast<const float4*>(F3 + i2 * 2);
        v0 += w0 * x0.x + w1 * x0.y + w2 * x0.z + w3 * x0.w;
        v1 += w0 * x1.x + w1 * x1.y + w2 * x1.z + w3 * x1.w;
        v2 += w0 * x2.x + w1 * x2.y + w2 * x2.z + w3 * x2.w;
        v3 += w0 * x3.x + w1 * x3.y + w2 * x3.z + w3 * x3.w;
    }

    out[(size_t)(r0 + 0) * 64 + o] = v0;
    out[(size_t)(r0 + 1) * 64 + o] = v1;
    out[(size_t)(r0 + 2) * 64 + o] = v2;
    out[(size_t)(r0 + 3) * 64 + o] = v3;
}

// ---------------- launch ----------------

extern "C" void kernel_launch(void* const* d_in, const int* in_sizes, int n_in,
                              void* d_out, int out_size, void* d_ws, size_t ws_size,
                              hipStream_t stream) {
    (void)in_sizes; (void)n_in; (void)out_size; (void)ws_size;
    const float* feat    = (const float*)d_in[0];
    const float* pos     = (const float*)d_in[1];
    const int*   src     = (const int*)d_in[2];
    const int*   dst     = (const int*)d_in[3];
    const float* W_self  = (const float*)d_in[4];
    const float* W_sp    = (const float*)d_in[5];
    const float* b_sp    = (const float*)d_in[6];
    const float* W_neigh = (const float*)d_in[7];
    const float* b_neigh = (const float*)d_in[8];
    const float* bias    = (const float*)d_in[9];
    float* out = (float*)d_out;

    // ws layout: accp[N*128] uint | cnt[N] | off[N+1] | cursor[N] | srcs[E] | bsum[49] | bofs[49]
    unsigned int* accp = (unsigned int*)d_ws;
    int* cnt    = (int*)(accp + (size_t)N_NODES * 128);
    int* off    = cnt + N_NODES;
    int* cursor = off + N_NODES + 1;
    int* srcs   = cursor + N_NODES;
    int* bsum   = srcs + N_EDGES;
    int* bofs   = bsum + SCAN_GRID;

    hipMemsetAsync(cnt, 0, N_NODES * sizeof(int), stream);
    hist_kernel<<<(N_EDGES + 255) / 256, 256, 0, stream>>>(dst, cnt);
    block_reduce_kernel<<<SCAN_GRID, SCAN_B, 0, stream>>>(cnt, bsum);
    scan_bsums_kernel<<<1, 64, 0, stream>>>(bsum, bofs);
    scan_write_kernel<<<SCAN_GRID, SCAN_B, 0, stream>>>(cnt, bofs, off, cursor);
    scatter_kernel<<<(N_EDGES + 255) / 256, 256, 0, stream>>>(src, dst, cursor, srcs);
    aggregate_kernel<<<N_NODES / 4, 256, 0, stream>>>(feat, pos, W_sp, b_sp, off, srcs, accp);
    project_kernel<<<N_NODES / 16, PRB, 0, stream>>>(feat, accp, W_neigh, W_self,
                                                     b_neigh, bias, out);
}

// Round 4
// 287.397 us; speedup vs baseline: 2.0432x; 1.1664x over previous
//
#include <hip/hip_runtime.h>
#include <math.h>

#define N_NODES 50000
#define N_EDGES 800000
#define EPS 1e-7f
#define NEG_SLOPE 0.01f

#define SCAN_B 1024
#define SCAN_GRID ((N_NODES + SCAN_B - 1) / SCAN_B)  // 49

typedef __attribute__((ext_vector_type(8))) short short8;
typedef __attribute__((ext_vector_type(4))) float f32x4;

// ---------------- CSR build ----------------

__global__ void hist_kernel(const int* __restrict__ dst, int* __restrict__ cnt) {
    int i = blockIdx.x * blockDim.x + threadIdx.x;
    if (i < N_EDGES) atomicAdd(&cnt[dst[i]], 1);
}

__global__ __launch_bounds__(SCAN_B) void block_reduce_kernel(const int* __restrict__ cnt,
                                                              int* __restrict__ bsum) {
    __shared__ int sd[SCAN_B];
    const int t = threadIdx.x;
    const int i = blockIdx.x * SCAN_B + t;
    sd[t] = (i < N_NODES) ? cnt[i] : 0;
    __syncthreads();
    for (int st = SCAN_B / 2; st > 0; st >>= 1) {
        if (t < st) sd[t] += sd[t + st];
        __syncthreads();
    }
    if (t == 0) bsum[blockIdx.x] = sd[0];
}

__global__ __launch_bounds__(64) void scan_bsums_kernel(const int* __restrict__ bsum,
                                                        int* __restrict__ bofs) {
    const int lane = threadIdx.x;
    int orig = (lane < SCAN_GRID) ? bsum[lane] : 0;
    int v = orig;
    for (int d = 1; d < 64; d <<= 1) {
        int u = __shfl_up(v, d, 64);
        if (lane >= d) v += u;
    }
    if (lane < SCAN_GRID) bofs[lane] = v - orig;  // exclusive
}

__global__ __launch_bounds__(SCAN_B) void scan_write_kernel(const int* __restrict__ cnt,
                                                            const int* __restrict__ bofs,
                                                            int* __restrict__ off,
                                                            int* __restrict__ cursor) {
    __shared__ int sd[SCAN_B];
    const int t = threadIdx.x;
    const int i = blockIdx.x * SCAN_B + t;
    const int v = (i < N_NODES) ? cnt[i] : 0;
    sd[t] = v;
    __syncthreads();
    for (int st = 1; st < SCAN_B; st <<= 1) {
        int u = (t >= st) ? sd[t - st] : 0;
        __syncthreads();
        sd[t] += u;
        __syncthreads();
    }
    const int excl = sd[t] - v + bofs[blockIdx.x];
    if (i < N_NODES) {
        off[i] = excl;
        cursor[i] = excl;
    }
    if (i == N_NODES - 1) off[N_NODES] = excl + v;  // == N_EDGES
}

__global__ void scatter_kernel(const int* __restrict__ src, const int* __restrict__ dst,
                               int* __restrict__ cursor, int* __restrict__ srcs) {
    int i = blockIdx.x * blockDim.x + threadIdx.x;
    if (i < N_EDGES) {
        int p = atomicAdd(&cursor[dst[i]], 1);
        srcs[p] = src[i];
    }
}

// ---------------- aggregation: one wave per node, no LDS ----------------

__device__ __forceinline__ unsigned pack_bf16(float a, float b) {
    return (__float_as_uint(a) >> 16) | (__float_as_uint(b) & 0xffff0000u);
}

__global__ __launch_bounds__(256) void aggregate_kernel(
    const float* __restrict__ feat, const float* __restrict__ pos,
    const float* __restrict__ W_sp, const float* __restrict__ b_sp,
    const int* __restrict__ off, const int* __restrict__ srcs,
    unsigned int* __restrict__ accp /* [N][128] bf16x2 */)
{
    const int lane = threadIdx.x & 63;
    const int n = (blockIdx.x << 2) + (threadIdx.x >> 6);  // 12500*4 == 50000 exact

    float wsp0[4], wsp1[4], wsp2[4], bsp[4];
#pragma unroll
    for (int h = 0; h < 4; ++h) {
        int j = lane * 4 + h;
        wsp0[h] = W_sp[j * 3 + 0];
        wsp1[h] = W_sp[j * 3 + 1];
        wsp2[h] = W_sp[j * 3 + 2];
        bsp[h]  = b_sp[j];
    }

    const int beg = __builtin_amdgcn_readfirstlane(off[n]);
    const int end = __builtin_amdgcn_readfirstlane(off[n + 1]);
    const float pdx = pos[n * 3 + 0];
    const float pdy = pos[n * 3 + 1];
    const float pdz = pos[n * 3 + 2];
    float a0 = 0.f, a1 = 0.f, a2 = 0.f, a3 = 0.f;

#define EDGE_BODY(SN, MSK)                                                      \
    {                                                                           \
        float rx = pdx - pos[(SN) * 3 + 0];                                     \
        float ry = pdy - pos[(SN) * 3 + 1];                                     \
        float rz = pdz - pos[(SN) * 3 + 2];                                     \
        float d  = rx * rx + ry * ry + rz * rz;                                 \
        float inv = __builtin_amdgcn_rcpf(__builtin_amdgcn_sqrtf(d) + EPS);     \
        float wx = (rx + 1.f) * inv;                                            \
        float wy = (ry + 1.f) * inv;                                            \
        float wz = (rz + 1.f) * inv;                                            \
        float f  = feat[(SN) * 64 + lane] * (MSK);                              \
        float t0 = wx * wsp0[0] + wy * wsp1[0] + wz * wsp2[0] + bsp[0];         \
        float t1 = wx * wsp0[1] + wy * wsp1[1] + wz * wsp2[1] + bsp[1];         \
        float t2 = wx * wsp0[2] + wy * wsp1[2] + wz * wsp2[2] + bsp[2];         \
        float t3 = wx * wsp0[3] + wy * wsp1[3] + wz * wsp2[3] + bsp[3];         \
        t0 = t0 > 0.f ? t0 : t0 * NEG_SLOPE;                                    \
        t1 = t1 > 0.f ? t1 : t1 * NEG_SLOPE;                                    \
        t2 = t2 > 0.f ? t2 : t2 * NEG_SLOPE;                                    \
        t3 = t3 > 0.f ? t3 : t3 * NEG_SLOPE;                                    \
        a0 += t0 * f; a1 += t1 * f; a2 += t2 * f; a3 += t3 * f;                 \
    }

    for (int k = beg; k < end; k += 4) {
        const int rem = end - k;
        const int k1 = k + (rem > 1 ? 1 : 0);
        const int k2 = k + (rem > 2 ? 2 : 0);
        const int k3 = k + (rem > 3 ? 3 : 0);
        const int s0 = __builtin_amdgcn_readfirstlane(srcs[k]);
        const int s1 = __builtin_amdgcn_readfirstlane(srcs[k1]);
        const int s2 = __builtin_amdgcn_readfirstlane(srcs[k2]);
        const int s3 = __builtin_amdgcn_readfirstlane(srcs[k3]);
        const float m1 = rem > 1 ? 1.f : 0.f;
        const float m2 = rem > 2 ? 1.f : 0.f;
        const float m3 = rem > 3 ? 1.f : 0.f;
        EDGE_BODY(s0, 1.f)
        EDGE_BODY(s1, m1)
        EDGE_BODY(s2, m2)
        EDGE_BODY(s3, m3)
    }
#undef EDGE_BODY

    const float mscale = 1.f / fmaxf((float)(end - beg), 1.f);
    a0 *= mscale; a1 *= mscale; a2 *= mscale; a3 *= mscale;
    uint2 pv = make_uint2(pack_bf16(a0, a1), pack_bf16(a2, a3));
    *reinterpret_cast<uint2*>(&accp[(size_t)n * 128 + lane * 2]) = pv;
}

// ---------------- weight pre-pack (f32 -> bf16), one block ----------------

__global__ __launch_bounds__(256) void pack_weights_kernel(
    const float* __restrict__ W_neigh, const float* __restrict__ W_self,
    const float* __restrict__ b_neigh, const float* __restrict__ bias,
    unsigned* __restrict__ wnp, unsigned* __restrict__ wsp, float* __restrict__ bb)
{
    const int t = threadIdx.x;
    const float2* Wn2 = (const float2*)W_neigh;
    const float2* Ws2 = (const float2*)W_self;
    for (int i = t; i < 64 * 128; i += 256) {   // 64x256 f32 -> 8192 packed uints
        float2 v = Wn2[i];
        wnp[i] = pack_bf16(v.x, v.y);
    }
    for (int i = t; i < 64 * 32; i += 256) {    // 64x64 f32 -> 2048 packed uints
        float2 v = Ws2[i];
        wsp[i] = pack_bf16(v.x, v.y);
    }
    if (t < 64) bb[t] = b_neigh[t] + bias[t];
}

// ---------------- projection via MFMA ----------------
// C[50000x64] = acc[50000x256](bf16) @ Wn^T + feat[50000x64](->bf16) @ Ws^T + bb
// Verified gfx950 16x16x32 bf16 layouts:
//   A: lane holds A[m=lane&15][k=(lane>>4)*8+j], j=0..7  (contiguous 16B)
//   B: lane holds B[k=(lane>>4)*8+j][n=lane&15]          (row n of W^T = row of W)
//   D: lane,reg r -> D[row=(lane>>4)*4+r][col=lane&15]

__device__ __forceinline__ short8 feat_frag_bf16(const float* p) {
    float4 x0 = *reinterpret_cast<const float4*>(p);
    float4 x1 = *reinterpret_cast<const float4*>(p + 4);
    union { unsigned u[4]; short8 s; } c;
    c.u[0] = pack_bf16(x0.x, x0.y);
    c.u[1] = pack_bf16(x0.z, x0.w);
    c.u[2] = pack_bf16(x1.x, x1.y);
    c.u[3] = pack_bf16(x1.z, x1.w);
    return c.s;
}

__global__ __launch_bounds__(256) void project_mfma_kernel(
    const float* __restrict__ feat, const short* __restrict__ accb,
    const short* __restrict__ wnb, const short* __restrict__ wsb,
    const float* __restrict__ bb, float* __restrict__ out)
{
    const int lane = threadIdx.x & 63;
    const int ct = threadIdx.x >> 6;        // wave = one 16-wide output col-tile
    const int nodeBase = blockIdx.x * 16;   // 3125 * 16 == 50000 exact, no tail
    const int mrow = lane & 15;
    const int quad = lane >> 4;
    const int o = ct * 16 + mrow;           // B column / output column

    f32x4 acc = {0.f, 0.f, 0.f, 0.f};

    const short* Ar = accb + (size_t)(nodeBase + mrow) * 256 + quad * 8;
    const short* Br = wnb + o * 256 + quad * 8;
#pragma unroll
    for (int ks = 0; ks < 8; ++ks) {
        short8 a = *reinterpret_cast<const short8*>(Ar + ks * 32);
        short8 b = *reinterpret_cast<const short8*>(Br + ks * 32);
        acc = __builtin_amdgcn_mfma_f32_16x16x32_bf16(a, b, acc, 0, 0, 0);
    }

    const float* Fr = feat + (size_t)(nodeBase + mrow) * 64 + quad * 8;
    const short* Sr = wsb + o * 64 + quad * 8;
#pragma unroll
    for (int ks = 0; ks < 2; ++ks) {
        short8 a = feat_frag_bf16(Fr + ks * 32);
        short8 b = *reinterpret_cast<const short8*>(Sr + ks * 32);
        acc = __builtin_amdgcn_mfma_f32_16x16x32_bf16(a, b, acc, 0, 0, 0);
    }

    const float badd = bb[o];
#pragma unroll
    for (int r = 0; r < 4; ++r) {
        out[(size_t)(nodeBase + quad * 4 + r) * 64 + o] = acc[r] + badd;
    }
}

// ---------------- launch ----------------

extern "C" void kernel_launch(void* const* d_in, const int* in_sizes, int n_in,
                              void* d_out, int out_size, void* d_ws, size_t ws_size,
                              hipStream_t stream) {
    (void)in_sizes; (void)n_in; (void)out_size; (void)ws_size;
    const float* feat    = (const float*)d_in[0];
    const float* pos     = (const float*)d_in[1];
    const int*   src     = (const int*)d_in[2];
    const int*   dst     = (const int*)d_in[3];
    const float* W_self  = (const float*)d_in[4];
    const float* W_sp    = (const float*)d_in[5];
    const float* b_sp    = (const float*)d_in[6];
    const float* W_neigh = (const float*)d_in[7];
    const float* b_neigh = (const float*)d_in[8];
    const float* bias    = (const float*)d_in[9];
    float* out = (float*)d_out;

    // ws layout (uints): accp[N*128] | wnp[8192] | wsp[2048] | bb[64]f |
    //                    cnt[N] | off[N+1] | cursor[N] | srcs[E] | bsum | bofs
    unsigned int* accp = (unsigned int*)d_ws;
    unsigned int* wnp  = accp + (size_t)N_NODES * 128;
    unsigned int* wsp  = wnp + 8192;
    float*        bb   = (float*)(wsp + 2048);
    int* cnt    = (int*)(bb + 64);
    int* off    = cnt + N_NODES;
    int* cursor = off + N_NODES + 1;
    int* srcs   = cursor + N_NODES;
    int* bsum   = srcs + N_EDGES;
    int* bofs   = bsum + SCAN_GRID;

    hipMemsetAsync(cnt, 0, N_NODES * sizeof(int), stream);
    pack_weights_kernel<<<1, 256, 0, stream>>>(W_neigh, W_self, b_neigh, bias, wnp, wsp, bb);
    hist_kernel<<<(N_EDGES + 255) / 256, 256, 0, stream>>>(dst, cnt);
    block_reduce_kernel<<<SCAN_GRID, SCAN_B, 0, stream>>>(cnt, bsum);
    scan_bsums_kernel<<<1, 64, 0, stream>>>(bsum, bofs);
    scan_write_kernel<<<SCAN_GRID, SCAN_B, 0, stream>>>(cnt, bofs, off, cursor);
    scatter_kernel<<<(N_EDGES + 255) / 256, 256, 0, stream>>>(src, dst, cursor, srcs);
    aggregate_kernel<<<N_NODES / 4, 256, 0, stream>>>(feat, pos, W_sp, b_sp, off, srcs, accp);
    project_mfma_kernel<<<N_NODES / 16, 256, 0, stream>>>(feat, (const short*)accp,
                                                          (const short*)wnp, (const short*)wsp,
                                                          bb, out);
}

// Round 5
// 245.332 us; speedup vs baseline: 2.3936x; 1.1715x over previous
//
#include <hip/hip_runtime.h>
#include <math.h>

#define N_NODES 50000
#define N_EDGES 800000
#define EPS 1e-7f
#define NEG_SLOPE 0.01f

#define SCAN_B 1024
#define SCAN_GRID ((N_NODES + SCAN_B - 1) / SCAN_B)  // 49

typedef __attribute__((ext_vector_type(8))) short short8;
typedef __attribute__((ext_vector_type(4))) float f32x4;

// ---------------- CSR build ----------------

// hist also records each edge's slot within its dst bucket -> scatter needs no atomics
__global__ void hist_kernel(const int* __restrict__ dst, int* __restrict__ cnt,
                            int* __restrict__ slot) {
    int i = blockIdx.x * blockDim.x + threadIdx.x;
    if (i < N_EDGES) slot[i] = atomicAdd(&cnt[dst[i]], 1);
}

__global__ __launch_bounds__(SCAN_B) void block_reduce_kernel(const int* __restrict__ cnt,
                                                              int* __restrict__ bsum) {
    __shared__ int sd[SCAN_B];
    const int t = threadIdx.x;
    const int i = blockIdx.x * SCAN_B + t;
    sd[t] = (i < N_NODES) ? cnt[i] : 0;
    __syncthreads();
    for (int st = SCAN_B / 2; st > 0; st >>= 1) {
        if (t < st) sd[t] += sd[t + st];
        __syncthreads();
    }
    if (t == 0) bsum[blockIdx.x] = sd[0];
}

__global__ __launch_bounds__(64) void scan_bsums_kernel(const int* __restrict__ bsum,
                                                        int* __restrict__ bofs) {
    const int lane = threadIdx.x;
    int orig = (lane < SCAN_GRID) ? bsum[lane] : 0;
    int v = orig;
    for (int d = 1; d < 64; d <<= 1) {
        int u = __shfl_up(v, d, 64);
        if (lane >= d) v += u;
    }
    if (lane < SCAN_GRID) bofs[lane] = v - orig;  // exclusive
}

__global__ __launch_bounds__(SCAN_B) void scan_write_kernel(const int* __restrict__ cnt,
                                                            const int* __restrict__ bofs,
                                                            int* __restrict__ off) {
    __shared__ int sd[SCAN_B];
    const int t = threadIdx.x;
    const int i = blockIdx.x * SCAN_B + t;
    const int v = (i < N_NODES) ? cnt[i] : 0;
    sd[t] = v;
    __syncthreads();
    for (int st = 1; st < SCAN_B; st <<= 1) {
        int u = (t >= st) ? sd[t - st] : 0;
        __syncthreads();
        sd[t] += u;
        __syncthreads();
    }
    const int excl = sd[t] - v + bofs[blockIdx.x];
    if (i < N_NODES) off[i] = excl;
    if (i == N_NODES - 1) off[N_NODES] = excl + v;  // == N_EDGES
}

// atomic-free scatter: position = off[dst] + slot
__global__ void scatter_kernel(const int* __restrict__ src, const int* __restrict__ dst,
                               const int* __restrict__ off, const int* __restrict__ slot,
                               int* __restrict__ srcs) {
    int i = blockIdx.x * blockDim.x + threadIdx.x;
    if (i < N_EDGES) {
        srcs[off[dst[i]] + slot[i]] = src[i];
    }
}

// ---------------- aggregation: phase-split, one wave per node ----------------

__device__ __forceinline__ unsigned pack_bf16(float a, float b) {
    return (__float_as_uint(a) >> 16) | (__float_as_uint(b) & 0xffff0000u);
}

__global__ __launch_bounds__(256) void aggregate_kernel(
    const float* __restrict__ feat, const float* __restrict__ pos,
    const float* __restrict__ W_sp, const float* __restrict__ b_sp,
    const int* __restrict__ off, const int* __restrict__ srcs,
    unsigned int* __restrict__ accp /* [N][128] bf16x2 */)
{
    __shared__ float4 gbuf[4][64];  // per-wave geometry staging (4 KB)

    const int lane = threadIdx.x & 63;
    const int w = threadIdx.x >> 6;
    const int nb = blockIdx.x << 2;
    const int n = nb + w;  // 12500*4 == 50000 exact

    // per-lane spatial-MLP rows: lane = feature i, handles j = lane*4+h
    float wsp0[4], wsp1[4], wsp2[4], bsp[4];
#pragma unroll
    for (int h = 0; h < 4; ++h) {
        int j = lane * 4 + h;
        wsp0[h] = W_sp[j * 3 + 0];
        wsp1[h] = W_sp[j * 3 + 1];
        wsp2[h] = W_sp[j * 3 + 2];
        bsp[h]  = b_sp[j];
    }

    // block-uniform chunk count: max degree over the block's 4 nodes
    const int o0 = off[nb + 0], o1 = off[nb + 1], o2 = off[nb + 2],
              o3 = off[nb + 3], o4 = off[nb + 4];
    int maxdeg = max(max(o1 - o0, o2 - o1), max(o3 - o2, o4 - o3));
    const int C = (maxdeg + 63) >> 6;

    const int beg = (w == 0) ? o0 : (w == 1) ? o1 : (w == 2) ? o2 : o3;
    const int end = (w == 0) ? o1 : (w == 1) ? o2 : (w == 2) ? o3 : o4;

    const float pdx = pos[n * 3 + 0];
    const float pdy = pos[n * 3 + 1];
    const float pdz = pos[n * 3 + 2];
    float a0 = 0.f, a1 = 0.f, a2 = 0.f, a3 = 0.f;

    for (int c = 0; c < C; ++c) {
        const int base = beg + (c << 6);
        int m = end - base; if (m > 64) m = 64;  // may be <= 0

        // phase A: lane = edge, compute geometry once per edge
        if (lane < m) {
            const int s = srcs[base + lane];
            const float rx = pdx - pos[s * 3 + 0];
            const float ry = pdy - pos[s * 3 + 1];
            const float rz = pdz - pos[s * 3 + 2];
            const float inv =
                __builtin_amdgcn_rcpf(__builtin_amdgcn_sqrtf(rx * rx + ry * ry + rz * rz) + EPS);
            gbuf[w][lane] = make_float4((rx + 1.f) * inv, (ry + 1.f) * inv,
                                        (rz + 1.f) * inv, __int_as_float(s));
        }
        __syncthreads();

        // phase B: lane = feature, loop edges (broadcast LDS reads)
        for (int e = 0; e < m; ++e) {
            const float4 g = gbuf[w][e];
            const int sb = __builtin_amdgcn_readfirstlane(__float_as_int(g.w));
            const float f = feat[(size_t)sb * 64 + lane];
            float t0 = fmaf(g.x, wsp0[0], fmaf(g.y, wsp1[0], fmaf(g.z, wsp2[0], bsp[0])));
            float t1 = fmaf(g.x, wsp0[1], fmaf(g.y, wsp1[1], fmaf(g.z, wsp2[1], bsp[1])));
            float t2 = fmaf(g.x, wsp0[2], fmaf(g.y, wsp1[2], fmaf(g.z, wsp2[2], bsp[2])));
            float t3 = fmaf(g.x, wsp0[3], fmaf(g.y, wsp1[3], fmaf(g.z, wsp2[3], bsp[3])));
            // leakyrelu(t) == max(t, 0.01t) for slope < 1
            a0 = fmaf(fmaxf(t0, t0 * NEG_SLOPE), f, a0);
            a1 = fmaf(fmaxf(t1, t1 * NEG_SLOPE), f, a1);
            a2 = fmaf(fmaxf(t2, t2 * NEG_SLOPE), f, a2);
            a3 = fmaf(fmaxf(t3, t3 * NEG_SLOPE), f, a3);
        }
        __syncthreads();
    }

    const float mscale = 1.f / fmaxf((float)(end - beg), 1.f);
    a0 *= mscale; a1 *= mscale; a2 *= mscale; a3 *= mscale;
    uint2 pv = make_uint2(pack_bf16(a0, a1), pack_bf16(a2, a3));
    *reinterpret_cast<uint2*>(&accp[(size_t)n * 128 + lane * 2]) = pv;
}

// ---------------- weight pre-pack (f32 -> bf16), one block ----------------

__global__ __launch_bounds__(256) void pack_weights_kernel(
    const float* __restrict__ W_neigh, const float* __restrict__ W_self,
    const float* __restrict__ b_neigh, const float* __restrict__ bias,
    unsigned* __restrict__ wnp, unsigned* __restrict__ wsp, float* __restrict__ bb)
{
    const int t = threadIdx.x;
    const float2* Wn2 = (const float2*)W_neigh;
    const float2* Ws2 = (const float2*)W_self;
    for (int i = t; i < 64 * 128; i += 256) {
        float2 v = Wn2[i];
        wnp[i] = pack_bf16(v.x, v.y);
    }
    for (int i = t; i < 64 * 32; i += 256) {
        float2 v = Ws2[i];
        wsp[i] = pack_bf16(v.x, v.y);
    }
    if (t < 64) bb[t] = b_neigh[t] + bias[t];
}

// ---------------- projection via MFMA ----------------

__device__ __forceinline__ short8 feat_frag_bf16(const float* p) {
    float4 x0 = *reinterpret_cast<const float4*>(p);
    float4 x1 = *reinterpret_cast<const float4*>(p + 4);
    union { unsigned u[4]; short8 s; } c;
    c.u[0] = pack_bf16(x0.x, x0.y);
    c.u[1] = pack_bf16(x0.z, x0.w);
    c.u[2] = pack_bf16(x1.x, x1.y);
    c.u[3] = pack_bf16(x1.z, x1.w);
    return c.s;
}

__global__ __launch_bounds__(256) void project_mfma_kernel(
    const float* __restrict__ feat, const short* __restrict__ accb,
    const short* __restrict__ wnb, const short* __restrict__ wsb,
    const float* __restrict__ bb, float* __restrict__ out)
{
    const int lane = threadIdx.x & 63;
    const int ct = threadIdx.x >> 6;
    const int nodeBase = blockIdx.x * 16;   // 3125 * 16 == 50000 exact
    const int mrow = lane & 15;
    const int quad = lane >> 4;
    const int o = ct * 16 + mrow;

    f32x4 acc = {0.f, 0.f, 0.f, 0.f};

    const short* Ar = accb + (size_t)(nodeBase + mrow) * 256 + quad * 8;
    const short* Br = wnb + o * 256 + quad * 8;
#pragma unroll
    for (int ks = 0; ks < 8; ++ks) {
        short8 a = *reinterpret_cast<const short8*>(Ar + ks * 32);
        short8 b = *reinterpret_cast<const short8*>(Br + ks * 32);
        acc = __builtin_amdgcn_mfma_f32_16x16x32_bf16(a, b, acc, 0, 0, 0);
    }

    const float* Fr = feat + (size_t)(nodeBase + mrow) * 64 + quad * 8;
    const short* Sr = wsb + o * 64 + quad * 8;
#pragma unroll
    for (int ks = 0; ks < 2; ++ks) {
        short8 a = feat_frag_bf16(Fr + ks * 32);
        short8 b = *reinterpret_cast<const short8*>(Sr + ks * 32);
        acc = __builtin_amdgcn_mfma_f32_16x16x32_bf16(a, b, acc, 0, 0, 0);
    }

    const float badd = bb[o];
#pragma unroll
    for (int r = 0; r < 4; ++r) {
        out[(size_t)(nodeBase + quad * 4 + r) * 64 + o] = acc[r] + badd;
    }
}

// ---------------- launch ----------------

extern "C" void kernel_launch(void* const* d_in, const int* in_sizes, int n_in,
                              void* d_out, int out_size, void* d_ws, size_t ws_size,
                              hipStream_t stream) {
    (void)in_sizes; (void)n_in; (void)out_size; (void)ws_size;
    const float* feat    = (const float*)d_in[0];
    const float* pos     = (const float*)d_in[1];
    const int*   src     = (const int*)d_in[2];
    const int*   dst     = (const int*)d_in[3];
    const float* W_self  = (const float*)d_in[4];
    const float* W_sp    = (const float*)d_in[5];
    const float* b_sp    = (const float*)d_in[6];
    const float* W_neigh = (const float*)d_in[7];
    const float* b_neigh = (const float*)d_in[8];
    const float* bias    = (const float*)d_in[9];
    float* out = (float*)d_out;

    // ws layout (uints): accp[N*128] | wnp[8192] | wsp[2048] | bb[64]f |
    //                    cnt[N] | off[N+1] | srcs[E] | slot[E] | bsum | bofs
    unsigned int* accp = (unsigned int*)d_ws;
    unsigned int* wnp  = accp + (size_t)N_NODES * 128;
    unsigned int* wsp  = wnp + 8192;
    float*        bb   = (float*)(wsp + 2048);
    int* cnt  = (int*)(bb + 64);
    int* off  = cnt + N_NODES;
    int* srcs = off + N_NODES + 1;
    int* slot = srcs + N_EDGES;
    int* bsum = slot + N_EDGES;
    int* bofs = bsum + SCAN_GRID;

    hipMemsetAsync(cnt, 0, N_NODES * sizeof(int), stream);
    pack_weights_kernel<<<1, 256, 0, stream>>>(W_neigh, W_self, b_neigh, bias, wnp, wsp, bb);
    hist_kernel<<<(N_EDGES + 255) / 256, 256, 0, stream>>>(dst, cnt, slot);
    block_reduce_kernel<<<SCAN_GRID, SCAN_B, 0, stream>>>(cnt, bsum);
    scan_bsums_kernel<<<1, 64, 0, stream>>>(bsum, bofs);
    scan_write_kernel<<<SCAN_GRID, SCAN_B, 0, stream>>>(cnt, bofs, off);
    scatter_kernel<<<(N_EDGES + 255) / 256, 256, 0, stream>>>(src, dst, off, slot, srcs);
    aggregate_kernel<<<N_NODES / 4, 256, 0, stream>>>(feat, pos, W_sp, b_sp, off, srcs, accp);
    project_mfma_kernel<<<N_NODES / 16, 256, 0, stream>>>(feat, (const short*)accp,
                                                          (const short*)wnp, (const short*)wsp,
                                                          bb, out);
}